// Round 2
// baseline (1693.634 us; speedup 1.0000x reference)
//
#include <hip/hip_runtime.h>
#include <math.h>

// Problem constants
#define NN   2048      // nodes
#define BB   16        // batch
#define CIN  2
#define HID  64
#define DD   16        // embed dim
#define C1   66        // CIN+HID
#define NC   1056      // B*C1
#define NCP  1152      // padded inner dim (18*64)
#define OG   128       // gate out
#define OU   64        // update out

// ---------------------------------------------------------------------------
// supports = softmax(relu(E @ E^T), axis=1) ; one block per row
// ---------------------------------------------------------------------------
__global__ __launch_bounds__(256) void support_softmax(const float* __restrict__ E,
                                                       float* __restrict__ S)
{
    const int n = blockIdx.x, t = threadIdx.x;
    __shared__ float red[4];
    float en[16];
#pragma unroll
    for (int d = 0; d < 16; ++d) en[d] = E[n * 16 + d];

    float v[8];
    float mx = 0.f;
#pragma unroll
    for (int j = 0; j < 8; ++j) {
        const int m = t + j * 256;
        const float4* ep = (const float4*)&E[m * 16];
        float4 e0 = ep[0], e1 = ep[1], e2 = ep[2], e3 = ep[3];
        float dot = en[0]*e0.x + en[1]*e0.y + en[2]*e0.z + en[3]*e0.w
                  + en[4]*e1.x + en[5]*e1.y + en[6]*e1.z + en[7]*e1.w
                  + en[8]*e2.x + en[9]*e2.y + en[10]*e2.z + en[11]*e2.w
                  + en[12]*e3.x + en[13]*e3.y + en[14]*e3.z + en[15]*e3.w;
        dot = fmaxf(dot, 0.f);
        v[j] = dot;
        mx = fmaxf(mx, dot);
    }
#pragma unroll
    for (int off = 32; off; off >>= 1) mx = fmaxf(mx, __shfl_down(mx, off, 64));
    const int wid = t >> 6, lane = t & 63;
    if (lane == 0) red[wid] = mx;
    __syncthreads();
    mx = fmaxf(fmaxf(red[0], red[1]), fmaxf(red[2], red[3]));

    float s = 0.f;
#pragma unroll
    for (int j = 0; j < 8; ++j) { v[j] = expf(v[j] - mx); s += v[j]; }
#pragma unroll
    for (int off = 32; off; off >>= 1) s += __shfl_down(s, off, 64);
    __syncthreads();
    if (lane == 0) red[wid] = s;
    __syncthreads();
    s = red[0] + red[1] + red[2] + red[3];
    const float inv = 1.f / s;
#pragma unroll
    for (int j = 0; j < 8; ++j) S[n * NN + t + j * 256] = v[j] * inv;
}

// ---------------------------------------------------------------------------
// Xcat[m][b*66+c] = c<2 ? X[b,m,c] : state[b,m,c-2]; pad cols [1056,1152) = 0
// ---------------------------------------------------------------------------
__global__ __launch_bounds__(256) void build_xcat(const float* __restrict__ X,
                                                  const float* __restrict__ state,
                                                  float* __restrict__ Xcat)
{
    const int idx = blockIdx.x * 256 + threadIdx.x;   // over NN*NCP
    const int m = idx / NCP, j = idx - m * NCP;
    float val = 0.f;
    if (j < NC) {
        const int b = j / C1, c = j - b * C1;
        val = (c < CIN) ? X[(b * NN + m) * CIN + c]
                        : state[(b * NN + m) * HID + (c - CIN)];
    }
    Xcat[m * NCP + j] = val;
}

// ---------------------------------------------------------------------------
// fp32 tiled GEMM: C[M,N] = A[M,K] * B[K,N]  (64x64 tile, BK=16, 4x4/thread)
// ---------------------------------------------------------------------------
__global__ __launch_bounds__(256) void gemm_f32(const float* __restrict__ A,
                                                const float* __restrict__ Bm,
                                                float* __restrict__ C,
                                                int lda, int ldb, int ldc, int Kdim)
{
    __shared__ __align__(16) float Ast[16][68];   // [k][m]
    __shared__ __align__(16) float Bst[16][68];   // [k][n]
    const int tid = threadIdx.x;
    const int m0 = blockIdx.y * 64, n0 = blockIdx.x * 64;
    const int tx = tid & 15, ty = tid >> 4;
    const int ar = tid >> 2, akq = (tid & 3) * 4;     // A load: row, k-quad
    const int bkr = tid >> 4, bcq = (tid & 15) * 4;   // B load: k-row, col-quad

    float acc[4][4] = {};
    for (int k0 = 0; k0 < Kdim; k0 += 16) {
        float4 av = *(const float4*)&A[(size_t)(m0 + ar) * lda + k0 + akq];
        float4 bv = *(const float4*)&Bm[(size_t)(k0 + bkr) * ldb + n0 + bcq];
        Ast[akq + 0][ar] = av.x;
        Ast[akq + 1][ar] = av.y;
        Ast[akq + 2][ar] = av.z;
        Ast[akq + 3][ar] = av.w;
        *(float4*)&Bst[bkr][bcq] = bv;
        __syncthreads();
#pragma unroll
        for (int kk = 0; kk < 16; ++kk) {
            float4 a = *(const float4*)&Ast[kk][ty * 4];
            float4 b = *(const float4*)&Bst[kk][tx * 4];
            float ai[4] = {a.x, a.y, a.z, a.w};
            float bj[4] = {b.x, b.y, b.z, b.w};
#pragma unroll
            for (int i = 0; i < 4; ++i)
#pragma unroll
                for (int j = 0; j < 4; ++j) acc[i][j] += ai[i] * bj[j];
        }
        __syncthreads();
    }
#pragma unroll
    for (int i = 0; i < 4; ++i) {
        float4 o = {acc[i][0], acc[i][1], acc[i][2], acc[i][3]};
        *(float4*)&C[(size_t)(m0 + ty * 4 + i) * ldc + n0 + tx * 4] = o;
    }
}

// ---------------------------------------------------------------------------
// Gate projection: per node n, W_n = sum_d E[n,d]*gate_W[d]  (132x128, 2 phases)
// y[b,o] = sum_ki xvec[b,ki]*W_n[ki,o] + bias ; sigmoid ; z->cand, r->rbuf
// ---------------------------------------------------------------------------
__global__ __launch_bounds__(256) void gate_proj(const float* __restrict__ E,
                                                 const float* __restrict__ gW,
                                                 const float* __restrict__ gb,
                                                 const float* __restrict__ Xcat,
                                                 const float* __restrict__ Zg,
                                                 const float* __restrict__ X,
                                                 const float* __restrict__ state,
                                                 float* __restrict__ cand,
                                                 float* __restrict__ rbuf)
{
    const int n = blockIdx.x, t = threadIdx.x;
    __shared__ __align__(16) float Wl[66 * 128];
    __shared__ float xv[NC], zv[NC];
    __shared__ float biasl[128];
    __shared__ float Er[16];

    if (t < 16) Er[t] = E[n * 16 + t];
    for (int idx = t; idx < NC; idx += 256) {
        xv[idx] = Xcat[(size_t)n * NCP + idx];
        zv[idx] = Zg[(size_t)n * NCP + idx];
    }
    if (t < 128) {
        float s = 0.f;
#pragma unroll
        for (int d = 0; d < 16; ++d) s += E[n * 16 + d] * gb[d * 128 + t];
        biasl[t] = s;
    }

    const int b = t >> 4, ob = (t & 15) * 8;
    float acc[8] = {};
    for (int p = 0; p < 2; ++p) {
        __syncthreads();   // fills visible / protect Wl reuse
#pragma unroll 1
        for (int e = 0; e < 33; ++e) {
            const int flat = t + e * 256;          // = ii*128 + o
            const int ii = flat >> 7, o = flat & 127;
            float s = 0.f;
#pragma unroll
            for (int d = 0; d < 16; ++d)
                s += Er[d] * gW[d * 16896 + (p * 66 + ii) * 128 + o];
            Wl[flat] = s;
        }
        __syncthreads();
        const float* v = p ? zv : xv;
        for (int ii = 0; ii < 66; ++ii) {
            const float xval = v[b * C1 + ii];
            float4 w0 = *(const float4*)&Wl[ii * 128 + ob];
            float4 w1 = *(const float4*)&Wl[ii * 128 + ob + 4];
            acc[0] += xval * w0.x; acc[1] += xval * w0.y;
            acc[2] += xval * w0.z; acc[3] += xval * w0.w;
            acc[4] += xval * w1.x; acc[5] += xval * w1.y;
            acc[6] += xval * w1.z; acc[7] += xval * w1.w;
        }
    }

#pragma unroll
    for (int q = 0; q < 8; ++q) {
        const int o = ob + q;
        const float y = acc[q] + biasl[o];
        const float sig = 1.f / (1.f + expf(-y));
        if (o < 64) {   // z
            cand[(size_t)n * NCP + b * C1 + CIN + o] = sig * state[(b * NN + n) * HID + o];
        } else {        // r
            rbuf[((size_t)n * BB + b) * HID + (o - 64)] = sig;
        }
    }
    if (t < 32) { const int bb = t >> 1, c = t & 1;
        cand[(size_t)n * NCP + bb * C1 + c] = X[(bb * NN + n) * CIN + c]; }
    if (t < 96) cand[(size_t)n * NCP + NC + t] = 0.f;
}

// ---------------------------------------------------------------------------
// Update projection + final combine:
// hc = tanh(xvec @ W_n + bias); h = r*state + (1-r)*hc
// ---------------------------------------------------------------------------
__global__ __launch_bounds__(256) void upd_proj(const float* __restrict__ E,
                                                const float* __restrict__ uW,
                                                const float* __restrict__ ub,
                                                const float* __restrict__ cand,
                                                const float* __restrict__ Zu,
                                                const float* __restrict__ state,
                                                const float* __restrict__ rbuf,
                                                float* __restrict__ out)
{
    const int n = blockIdx.x, t = threadIdx.x;
    __shared__ __align__(16) float Wl[132 * 64];
    __shared__ float xv[NC], zv[NC];
    __shared__ float biasl[64];
    __shared__ float Er[16];

    if (t < 16) Er[t] = E[n * 16 + t];
    for (int idx = t; idx < NC; idx += 256) {
        xv[idx] = cand[(size_t)n * NCP + idx];
        zv[idx] = Zu[(size_t)n * NCP + idx];
    }
    if (t < 64) {
        float s = 0.f;
#pragma unroll
        for (int d = 0; d < 16; ++d) s += E[n * 16 + d] * ub[d * 64 + t];
        biasl[t] = s;
    }
    __syncthreads();
#pragma unroll 1
    for (int e = 0; e < 33; ++e) {
        const int flat = t + e * 256;              // = ki*64 + o
        float s = 0.f;
#pragma unroll
        for (int d = 0; d < 16; ++d) s += Er[d] * uW[d * 8448 + flat];
        Wl[flat] = s;
    }
    __syncthreads();

    const int b = t >> 4, ob = (t & 15) * 4;
    float acc[4] = {};
    for (int ii = 0; ii < 66; ++ii) {
        const float xval = xv[b * C1 + ii];
        float4 w = *(const float4*)&Wl[ii * 64 + ob];
        acc[0] += xval * w.x; acc[1] += xval * w.y;
        acc[2] += xval * w.z; acc[3] += xval * w.w;
    }
    for (int ii = 0; ii < 66; ++ii) {
        const float xval = zv[b * C1 + ii];
        float4 w = *(const float4*)&Wl[(66 + ii) * 64 + ob];
        acc[0] += xval * w.x; acc[1] += xval * w.y;
        acc[2] += xval * w.z; acc[3] += xval * w.w;
    }
#pragma unroll
    for (int q = 0; q < 4; ++q) {
        const int o = ob + q;
        const float hc = tanhf(acc[q] + biasl[o]);
        const float r = rbuf[((size_t)n * BB + b) * HID + o];
        const float st = state[(b * NN + n) * HID + o];
        out[(size_t)(b * NN + n) * HID + o] = r * st + (1.f - r) * hc;
    }
}

// ---------------------------------------------------------------------------
extern "C" void kernel_launch(void* const* d_in, const int* in_sizes, int n_in,
                              void* d_out, int out_size, void* d_ws, size_t ws_size,
                              hipStream_t stream)
{
    const float* X     = (const float*)d_in[0];
    const float* state = (const float*)d_in[1];
    const float* E     = (const float*)d_in[2];
    const float* gW    = (const float*)d_in[3];
    const float* gb    = (const float*)d_in[4];
    const float* uW    = (const float*)d_in[5];
    const float* ub    = (const float*)d_in[6];
    float* out = (float*)d_out;

    float* ws   = (float*)d_ws;
    float* S    = ws;                       // 2048*2048
    float* Xcat = S    + (size_t)NN * NN;   // 2048*1152
    float* Zg   = Xcat + (size_t)NN * NCP;
    float* cand = Zg   + (size_t)NN * NCP;
    float* Zu   = cand + (size_t)NN * NCP;
    float* rbuf = Zu   + (size_t)NN * NCP;  // 2048*16*64

    support_softmax<<<NN, 256, 0, stream>>>(E, S);
    build_xcat<<<(NN * NCP) / 256, 256, 0, stream>>>(X, state, Xcat);
    gemm_f32<<<dim3(NCP / 64, NN / 64), 256, 0, stream>>>(S, Xcat, Zg, NN, NCP, NCP, NN);
    gate_proj<<<NN, 256, 0, stream>>>(E, gW, gb, Xcat, Zg, X, state, cand, rbuf);
    gemm_f32<<<dim3(NCP / 64, NN / 64), 256, 0, stream>>>(S, cand, Zu, NN, NCP, NCP, NN);
    upd_proj<<<NN, 256, 0, stream>>>(E, uW, ub, cand, Zu, state, rbuf, out);
}

// Round 4
// 305.483 us; speedup vs baseline: 5.5441x; 5.5441x over previous
//
#include <hip/hip_runtime.h>
#include <math.h>

#define NN   2048
#define BB   16
#define CINC 2
#define HID  64
#define C1   66
#define NC   1056      // 16*66
#define NCP  1152      // padded col dim
#define KI   132       // 2*66 contraction length
#define KIP  168       // LDS A row pitch (>=160, 8-elem aligned, conflict-friendly)

typedef unsigned short u16;
typedef __attribute__((ext_vector_type(8))) short bf16x8;
typedef __attribute__((ext_vector_type(4))) float f32x4;

__device__ __forceinline__ u16 f2bf(float f) {
    union { float f; unsigned int u; } v; v.f = f;
    unsigned int r = (v.u + 0x7FFFu + ((v.u >> 16) & 1u)) >> 16;
    return (u16)r;
}
__device__ __forceinline__ float bf2f(u16 h) {
    union { unsigned int u; float f; } v; v.u = ((unsigned int)h) << 16;
    return v.f;
}

// ---------------------------------------------------------------------------
// S_bf[n][m] = softmax_m(relu(E@E^T)) in bf16
// ---------------------------------------------------------------------------
__global__ __launch_bounds__(256) void support_softmax(const float* __restrict__ E,
                                                       u16* __restrict__ S)
{
    const int n = blockIdx.x, t = threadIdx.x;
    __shared__ float red[4];
    float en[16];
#pragma unroll
    for (int d = 0; d < 16; ++d) en[d] = E[n * 16 + d];

    float v[8]; float mx = 0.f;
#pragma unroll
    for (int j = 0; j < 8; ++j) {
        const int m = t + j * 256;
        const float4* ep = (const float4*)&E[m * 16];
        float4 e0 = ep[0], e1 = ep[1], e2 = ep[2], e3 = ep[3];
        float dot = en[0]*e0.x + en[1]*e0.y + en[2]*e0.z + en[3]*e0.w
                  + en[4]*e1.x + en[5]*e1.y + en[6]*e1.z + en[7]*e1.w
                  + en[8]*e2.x + en[9]*e2.y + en[10]*e2.z + en[11]*e2.w
                  + en[12]*e3.x + en[13]*e3.y + en[14]*e3.z + en[15]*e3.w;
        dot = fmaxf(dot, 0.f);
        v[j] = dot; mx = fmaxf(mx, dot);
    }
#pragma unroll
    for (int off = 32; off; off >>= 1) mx = fmaxf(mx, __shfl_down(mx, off, 64));
    const int wid = t >> 6, lane = t & 63;
    if (lane == 0) red[wid] = mx;
    __syncthreads();
    mx = fmaxf(fmaxf(red[0], red[1]), fmaxf(red[2], red[3]));

    float s = 0.f;
#pragma unroll
    for (int j = 0; j < 8; ++j) { v[j] = expf(v[j] - mx); s += v[j]; }
#pragma unroll
    for (int off = 32; off; off >>= 1) s += __shfl_down(s, off, 64);
    __syncthreads();
    if (lane == 0) red[wid] = s;
    __syncthreads();
    s = red[0] + red[1] + red[2] + red[3];
    const float inv = 1.f / s;
#pragma unroll
    for (int j = 0; j < 8; ++j) S[n * NN + t + j * 256] = f2bf(v[j] * inv);
}

// ---------------------------------------------------------------------------
// XcatT[j][m] (bf16, [1152][2048]); rows j>=1056 zero
// ---------------------------------------------------------------------------
__global__ __launch_bounds__(256) void build_xcatT(const float* __restrict__ X,
                                                   const float* __restrict__ state,
                                                   u16* __restrict__ XT)
{
    const int idx = blockIdx.x * 256 + threadIdx.x;   // over 1152*2048
    const int m = idx & (NN - 1), j = idx >> 11;
    float val = 0.f;
    if (j < NC) {
        const int b = j / C1, c = j - b * C1;
        val = (c < CINC) ? X[(b * NN + m) * CINC + c]
                         : state[(b * NN + m) * HID + (c - CINC)];
    }
    XT[(size_t)j * NN + m] = f2bf(val);
}

// ---------------------------------------------------------------------------
// bias_all[n][o] = sum_d E[n,d]*bvec[d,o]  (fp32)
// ---------------------------------------------------------------------------
template<int O>
__global__ __launch_bounds__(256) void bias_build(const float* __restrict__ E,
                                                  const float* __restrict__ bvec,
                                                  float* __restrict__ bias)
{
    const int idx = blockIdx.x * 256 + threadIdx.x;
    const int o = idx % O, n = idx / O;
    float s = 0.f;
#pragma unroll
    for (int d = 0; d < 16; ++d) s += E[n * 16 + d] * bvec[d * O + o];
    bias[idx] = s;
}

// ---------------------------------------------------------------------------
// W_all[n][ki][o] bf16 = sum_d E[n,d] * Wp[d][ki][o]   (16 nodes per block)
// ---------------------------------------------------------------------------
template<int O>
__global__ __launch_bounds__(256) void wbuild(const float* __restrict__ E,
                                              const float* __restrict__ Wp,
                                              u16* __restrict__ Wall)
{
    const int t = threadIdx.x;
    const int n0 = blockIdx.y * 16;
    __shared__ float El[256];
    El[t] = E[n0 * 16 + t];
    __syncthreads();

    const int nchunks = (KI * O) / 256;
    for (int ch = blockIdx.x; ch < nchunks; ch += gridDim.x) {
        const int flat = ch * 256 + t;          // = ki*O + o
        float w[16];
#pragma unroll
        for (int d = 0; d < 16; ++d) w[d] = Wp[d * (KI * O) + flat];
#pragma unroll 4
        for (int g = 0; g < 16; ++g) {
            float s = 0.f;
#pragma unroll
            for (int d = 0; d < 16; ++d) s += El[g * 16 + d] * w[d];
            Wall[(size_t)(n0 + g) * (KI * O) + flat] = f2bf(s);
        }
    }
}

// ---------------------------------------------------------------------------
// bf16 MFMA GEMM: C[2048][1152](bf16) = A[2048][2048] * BT[1152][2048]^T
// 64x64 tile, BK=32, 4 waves (each 32x32), 16x16x32 MFMA
// ---------------------------------------------------------------------------
__global__ __launch_bounds__(256) void gemm64(const u16* __restrict__ A,
                                              const u16* __restrict__ BT,
                                              u16* __restrict__ C)
{
    __shared__ u16 As[64 * 32];
    __shared__ u16 Bs[64 * 32];
    const int t = threadIdx.x, w = t >> 6, l = t & 63;
    const int m0 = blockIdx.y * 64, n0 = blockIdx.x * 64;
    const int wm = (w >> 1) * 32, wn = (w & 1) * 32;

    // staging map: row = w*16 + (l>>2), col8 = (l&3)*8
    const int srow = w * 16 + (l >> 2), scol = (l & 3) * 8;
    const size_t ga0 = (size_t)(m0 + srow) * NN + scol;
    const size_t gb0 = (size_t)(n0 + srow) * NN + scol;
    const int soff = srow * 32 + scol;

    f32x4 acc[2][2];
#pragma unroll
    for (int i = 0; i < 2; ++i)
#pragma unroll
        for (int j = 0; j < 2; ++j) acc[i][j] = f32x4{0.f, 0.f, 0.f, 0.f};

    for (int k0 = 0; k0 < NN; k0 += 32) {
        bf16x8 av = *(const bf16x8*)&A[ga0 + k0];
        bf16x8 bv = *(const bf16x8*)&BT[gb0 + k0];
        *(bf16x8*)&As[soff] = av;
        *(bf16x8*)&Bs[soff] = bv;
        __syncthreads();
        bf16x8 af[2], bfr[2];
#pragma unroll
        for (int mi = 0; mi < 2; ++mi)
            af[mi] = *(const bf16x8*)&As[(wm + mi * 16 + (l & 15)) * 32 + (l >> 4) * 8];
#pragma unroll
        for (int nj = 0; nj < 2; ++nj)
            bfr[nj] = *(const bf16x8*)&Bs[(wn + nj * 16 + (l & 15)) * 32 + (l >> 4) * 8];
#pragma unroll
        for (int mi = 0; mi < 2; ++mi)
#pragma unroll
            for (int nj = 0; nj < 2; ++nj)
                acc[mi][nj] = __builtin_amdgcn_mfma_f32_16x16x32_bf16(af[mi], bfr[nj], acc[mi][nj], 0, 0, 0);
        __syncthreads();
    }
#pragma unroll
    for (int mi = 0; mi < 2; ++mi)
#pragma unroll
        for (int nj = 0; nj < 2; ++nj)
#pragma unroll
            for (int q = 0; q < 4; ++q) {
                const int row = m0 + wm + mi * 16 + (l >> 4) * 4 + q;
                const int col = n0 + wn + nj * 16 + (l & 15);
                C[(size_t)row * NCP + col] = f2bf(acc[mi][nj][q]);
            }
}

// ---------------------------------------------------------------------------
// Gate apply: per node (1 wave each, 4 nodes/block):
// A[16 x 132] = [X|state (bf16) | Zg row], W from Wg[n][ki][128]
// y=sigmoid(A@W+bias): z*state -> candRow (bf16), r -> rbuf (fp32)
// ---------------------------------------------------------------------------
__global__ __launch_bounds__(256) void apply_gate(const u16* __restrict__ Wg,
                                                  const float* __restrict__ biasg,
                                                  const float* __restrict__ X,
                                                  const float* __restrict__ state,
                                                  const u16* __restrict__ Zg,
                                                  u16* __restrict__ candRow,
                                                  float* __restrict__ rbuf)
{
    const int t = threadIdx.x, wv = t >> 6, l = t & 63;
    const int node = blockIdx.x * 4 + wv;
    __shared__ u16 Al[4][16 * KIP];
    u16* base = Al[wv];

    for (int i = l; i < 16 * KIP; i += 64) base[i] = 0;
    // k=0 : X cols 0..1, state cols 2..65
    for (int f = l; f < 32; f += 64) {
        const int b = f >> 1, c = f & 1;
        base[b * KIP + c] = f2bf(X[(b * NN + node) * CINC + c]);
    }
#pragma unroll
    for (int k = 0; k < 16; ++k)
        base[k * KIP + 2 + l] = f2bf(state[(k * NN + node) * HID + l]);
    // k=1 : Zg row -> kidx 66..131
    for (int f = l; f < NC; f += 64) {
        const int b = f / C1, i = f - b * C1;
        base[b * KIP + C1 + i] = Zg[(size_t)node * NCP + f];
    }
    __syncthreads();

    bf16x8 aF[5];
#pragma unroll
    for (int kc = 0; kc < 5; ++kc)
        aF[kc] = *(const bf16x8*)&base[(l & 15) * KIP + kc * 32 + (l >> 4) * 8];

    const u16* wp_n = Wg + (size_t)node * (KI * 128);
#pragma unroll 2
    for (int ct = 0; ct < 8; ++ct) {
        f32x4 acc = f32x4{0.f, 0.f, 0.f, 0.f};
#pragma unroll
        for (int kc = 0; kc < 5; ++kc) {
            const u16* wp = wp_n + (size_t)(kc * 32 + (l >> 4) * 8) * 128 + ct * 16 + (l & 15);
            bf16x8 bF;
#pragma unroll
            for (int j = 0; j < 8; ++j) bF[j] = (short)wp[j * 128];
            acc = __builtin_amdgcn_mfma_f32_16x16x32_bf16(aF[kc], bF, acc, 0, 0, 0);
        }
#pragma unroll
        for (int q = 0; q < 4; ++q) {
            const int b = (l >> 4) * 4 + q;
            const int o = ct * 16 + (l & 15);
            const float y = acc[q] + biasg[node * 128 + o];
            const float sg = 1.f / (1.f + expf(-y));
            if (o < 64) {
                candRow[(size_t)node * NCP + b * C1 + CINC + o] =
                    f2bf(sg * state[(b * NN + node) * HID + o]);
            } else {
                rbuf[((size_t)node * BB + b) * HID + (o - 64)] = sg;
            }
        }
    }
    // candRow X part
    for (int f = l; f < 32; f += 64) {
        const int b = f >> 1, c = f & 1;
        candRow[(size_t)node * NCP + b * C1 + c] = f2bf(X[(b * NN + node) * CINC + c]);
    }
}

// ---------------------------------------------------------------------------
// candT[j][m] = candRow[m][j]; rows j>=1056 zeroed
// ---------------------------------------------------------------------------
__global__ __launch_bounds__(256) void transpose_pad(const u16* __restrict__ in,
                                                     u16* __restrict__ out)
{
    __shared__ u16 tile[64][65];
    const int t = threadIdx.x;
    const int j0 = blockIdx.x * 64, m0 = blockIdx.y * 64;
    for (int r = t >> 6; r < 64; r += 4)
        tile[r][t & 63] = in[(size_t)(m0 + r) * NCP + j0 + (t & 63)];
    __syncthreads();
    for (int r = t >> 6; r < 64; r += 4) {
        const int j = j0 + r;
        const u16 val = (j < NC) ? tile[t & 63][r] : (u16)0;
        out[(size_t)j * NN + m0 + (t & 63)] = val;
    }
}

// ---------------------------------------------------------------------------
// Update apply + combine: hc=tanh(A@Wu+bias); h=r*state+(1-r)*hc
// ---------------------------------------------------------------------------
__global__ __launch_bounds__(256) void apply_upd(const u16* __restrict__ Wu,
                                                 const float* __restrict__ biasu,
                                                 const u16* __restrict__ candRow,
                                                 const u16* __restrict__ Zu,
                                                 const float* __restrict__ state,
                                                 const float* __restrict__ rbuf,
                                                 float* __restrict__ out)
{
    const int t = threadIdx.x, wv = t >> 6, l = t & 63;
    const int node = blockIdx.x * 4 + wv;
    __shared__ u16 Al[4][16 * KIP];
    u16* base = Al[wv];

    for (int i = l; i < 16 * KIP; i += 64) base[i] = 0;
    for (int f = l; f < NC; f += 64) {
        const int b = f / C1, i = f - b * C1;
        base[b * KIP + i]      = candRow[(size_t)node * NCP + f];
        base[b * KIP + C1 + i] = Zu[(size_t)node * NCP + f];
    }
    __syncthreads();

    bf16x8 aF[5];
#pragma unroll
    for (int kc = 0; kc < 5; ++kc)
        aF[kc] = *(const bf16x8*)&base[(l & 15) * KIP + kc * 32 + (l >> 4) * 8];

    const u16* wp_n = Wu + (size_t)node * (KI * 64);
#pragma unroll 2
    for (int ct = 0; ct < 4; ++ct) {
        f32x4 acc = f32x4{0.f, 0.f, 0.f, 0.f};
#pragma unroll
        for (int kc = 0; kc < 5; ++kc) {
            const u16* wp = wp_n + (size_t)(kc * 32 + (l >> 4) * 8) * 64 + ct * 16 + (l & 15);
            bf16x8 bF;
#pragma unroll
            for (int j = 0; j < 8; ++j) bF[j] = (short)wp[j * 64];
            acc = __builtin_amdgcn_mfma_f32_16x16x32_bf16(aF[kc], bF, acc, 0, 0, 0);
        }
#pragma unroll
        for (int q = 0; q < 4; ++q) {
            const int b = (l >> 4) * 4 + q;
            const int o = ct * 16 + (l & 15);
            const float hc = tanhf(acc[q] + biasu[node * 64 + o]);
            const float r  = rbuf[((size_t)node * BB + b) * HID + o];
            const float st = state[(b * NN + node) * HID + o];
            out[(size_t)(b * NN + node) * HID + o] = r * st + (1.f - r) * hc;
        }
    }
}

// ---------------------------------------------------------------------------
extern "C" void kernel_launch(void* const* d_in, const int* in_sizes, int n_in,
                              void* d_out, int out_size, void* d_ws, size_t ws_size,
                              hipStream_t stream)
{
    const float* X     = (const float*)d_in[0];
    const float* state = (const float*)d_in[1];
    const float* E     = (const float*)d_in[2];
    const float* gW    = (const float*)d_in[3];
    const float* gb    = (const float*)d_in[4];
    const float* uW    = (const float*)d_in[5];
    const float* ub    = (const float*)d_in[6];
    float* out = (float*)d_out;

    char* ws = (char*)d_ws;
    u16*   S_bf   = (u16*)(ws);                         // 8,388,608
    u16*   XcatT  = (u16*)(ws + 8388608);               // 4,718,592
    u16*   Zg     = (u16*)(ws + 13107200);              // 4,718,592
    u16*   candR  = (u16*)(ws + 17825792);              // 4,718,592
    u16*   candT  = (u16*)(ws + 22544384);              // 4,718,592
    u16*   Zu     = (u16*)(ws + 27262976);              // 4,718,592
    u16*   Wreg   = (u16*)(ws + 31981568);              // 69,206,016 (+64K pad)
    float* rbuf   = (float*)(ws + 101253120);           // 8,388,608
    float* biasg  = (float*)(ws + 109641728);           // 1,048,576
    float* biasu  = (float*)(ws + 110690304);           // 524,288  -> total ~106 MB

    support_softmax<<<NN, 256, 0, stream>>>(E, S_bf);
    build_xcatT<<<(NCP * NN) / 256, 256, 0, stream>>>(X, state, XcatT);
    bias_build<128><<<(NN * 128) / 256, 256, 0, stream>>>(E, gb, biasg);
    bias_build<64><<<(NN * 64) / 256, 256, 0, stream>>>(E, ub, biasu);
    wbuild<128><<<dim3(4, 128), 256, 0, stream>>>(E, gW, Wreg);
    gemm64<<<dim3(NCP / 64, NN / 64), 256, 0, stream>>>(S_bf, XcatT, Zg);
    apply_gate<<<NN / 4, 256, 0, stream>>>(Wreg, biasg, X, state, Zg, candR, rbuf);
    wbuild<64><<<dim3(4, 128), 256, 0, stream>>>(E, uW, Wreg);   // reuse Wreg after gate
    transpose_pad<<<dim3(NCP / 64, NN / 64), 256, 0, stream>>>(candR, candT);
    gemm64<<<dim3(NCP / 64, NN / 64), 256, 0, stream>>>(S_bf, candT, Zu);
    apply_upd<<<NN / 4, 256, 0, stream>>>(Wreg, biasu, candR, Zu, state, rbuf, out);
}